// Round 13
// baseline (29.360 us; speedup 1.0000x reference)
//
#include <hip/hip_runtime.h>
#include <math.h>

// Banded unbalanced Sinkhorn OT -> disparity. One (b,h) problem per block,
// 6 waves. ONE block barrier per Sinkhorn iteration: wave w owns rows
// j in [52w,52w+52) and redundantly computes the 99 G values those rows
// need (G published to a wave-private LDS strip; intra-wave ordering via
// lgkmcnt(0), no barrier). E=2^f is double-buffered fp16 with even/odd
// shifted replicas; col weights staged per-column in LDS (pair-packed,
// stride-25 dwords); row weights in registers. Uniform shifts ride in an
// end-of-kernel scalar recurrence over 21 reduction values.

typedef _Float16 half1;
typedef _Float16 half2v __attribute__((ext_vector_type(2)));

#define MAXD   48
#define WROWS  312
#define CCOLS  360
#define NITER  10
#define NT     384
#define NWAVE  6
#define NACC   21
#define WCS    25      // wC2 row stride (dwords), odd -> conflict-free
#define GSS    52      // G strip stride per wave (dwords)

__device__ __forceinline__ half2v h2(unsigned v) { return __builtin_bit_cast(half2v, v); }
__device__ __forceinline__ unsigned packf(float x, float y) {
    half2v v; v[0] = (half1)x; v[1] = (half1)y;
    return __builtin_bit_cast(unsigned, v);
}
__device__ __forceinline__ float fdot2(unsigned a, unsigned b, float c) {
    return __builtin_amdgcn_fdot2(h2(a), h2(b), c, false);
}
__device__ __forceinline__ float fdot2h(half2v a, unsigned b, float c) {
    return __builtin_amdgcn_fdot2(a, h2(b), c, false);
}
template <int CTRL>
__device__ __forceinline__ float dpp_add(float x, float acc) {
    int y = __builtin_amdgcn_update_dpp(0, __float_as_int(x), CTRL, 0xf, 0xf, true);
    return acc + __int_as_float(y);
}
__device__ __forceinline__ float dpp_sum64(float x) {   // valid in lane 63
    x = dpp_add<0x111>(x, x);
    x = dpp_add<0x112>(x, x);
    x = dpp_add<0x114>(x, x);
    x = dpp_add<0x118>(x, x);
    x = dpp_add<0x142>(x, x);
    x = dpp_add<0x143>(x, x);
    return x;
}

__global__ __launch_bounds__(NT, 2)
void ot_disp_kernel(const float* __restrict__ scores, float* __restrict__ out) {
    const int tid = threadIdx.x;
    const int wid = tid >> 6;
    const int L   = tid & 63;
    const int bid = blockIdx.x;                 // 0..127 (= b*64 + h)
    const int b   = bid >> 6, h = bid & 63;

    const float LOG_A2 = -8.2854022f;   // -log2(312)
    const float LOG_B2 = -8.4918531f;   // -log2(360)
    const float TAU = 0.95f, KAPPA = 0.025f, XI = 0.025641026f;
    const float RHO = 19.0f, INVRHO = 0.052631579f, TIR = 0.05f;

    // wC2[c][t] = (w[2t][c-48+2t], w[2t+1][c-47+2t]) fp16-pair, stride 25
    __shared__ unsigned wC2[CCOLS * WCS];          // 36.0 KB
    // E buffers: [buf][parity][204] dwords; parity0 halfs p, parity1 halfs p+1
    __shared__ unsigned Ebuf[2][2][204];           // 6.5 KB
    // per-wave G strips: GSA halfs q, GSB halfs q+1 (q = c - 52w - 1)
    __shared__ unsigned GSA[NWAVE * GSS], GSB[NWAVE * GSS];
    __shared__ float s_red[NACC * NWAVE];

    const float* src = scores + ((size_t)(b * MAXD) * 64 + h) * WROWS;
    const size_t dstr = (size_t)64 * WROWS;

    // ---- zero E buffers (guards; written range never needs re-zero) ----
    {
        unsigned* ez = &Ebuf[0][0][0];
        #pragma unroll
        for (int k = 0; k < 3; ++k) {
            int i = tid + k * NT;
            if (i < 816) ez[i] = 0u;
        }
    }

    // ---- stage per-column weights (coalesced global reads) ----
    #pragma unroll 1
    for (int t = 0; t < 24; ++t) {
        int c = tid;
        if (c < CCOLS) {
            int j0 = c - MAXD + 2 * t, j1 = j0 + 1;
            bool v0 = (unsigned)j0 < (unsigned)WROWS;
            bool v1 = (unsigned)j1 < (unsigned)WROWS;
            float x0 = v0 ? __expf(src[(size_t)(2 * t) * dstr + (v0 ? j0 : 0)]) : 0.f;
            float x1 = v1 ? __expf(src[(size_t)(2 * t + 1) * dstr + (v1 ? j1 : 0)]) : 0.f;
            wC2[c * WCS + t] = packf(x0, x1);
        }
    }

    // ---- row weights in registers ----
    const bool rowAct = (L < 52);
    const int  j  = 52 * wid + (rowAct ? L : 51);
    unsigned wrow[24];   // pair t = (w_{d=47-2t}, w_{d=46-2t})
    {
        const float rm = rowAct ? 1.f : 0.f;
        #pragma unroll
        for (int t = 0; t < 24; ++t) {
            float x0 = rm * __expf(src[(size_t)(47 - 2 * t) * dstr + j]);
            float x1 = rm * __expf(src[(size_t)(46 - 2 * t) * dstr + j]);
            wrow[t] = packf(x0, x1);
        }
    }

    // ---- init: Ehat0 = 1/sum(w_row); y0 -> s_red[0] ----
    const unsigned ONE2 = 0x3C003C00u;
    {
        float s0 = 0.f, s1 = 0.f;
        #pragma unroll
        for (int t = 0; t < 24; t += 2) {
            s0 = fdot2(wrow[t], ONE2, s0);
            s1 = fdot2(wrow[t + 1], ONE2, s1);
        }
        float l  = __builtin_amdgcn_logf(s0 + s1);
        float e0 = __builtin_amdgcn_exp2f(-l);
        if (rowAct) {
            ((half1*)Ebuf[0][0])[j + 48] = (half1)e0;
            ((half1*)Ebuf[0][1])[j + 49] = (half1)e0;
        }
        float y0 = __builtin_amdgcn_exp2f(fmaf(INVRHO, l, LOG_A2));  // 0 for idle
        float ts = dpp_sum64(y0);
        if (L == 63) s_red[0 * NWAVE + wid] = ts;
    }
    __syncthreads();   // B0: E0 + wC2 + zeros visible

    // ---- per-lane G assignment (fixed) ----
    const int  c0   = 52 * wid + 1 + L;          // always <= 324
    const bool v1   = (L < 35);                  // second slot c1 = c0+64 (<360)
    const int  cOff = v1 ? 64 : 0;
    const int  par  = c0 & 1;
    const int  bdw  = (c0 + par) >> 1;           // window base dword
    const unsigned* const wc = wC2 + c0 * WCS;
    const int  lo = (wid < 5) ? (60 * wid + 1) : 301;   // y-ownership range
    const int  nn = (wid < 5) ? 60 : 59;
    const bool own0 = (unsigned)(c0 - lo) < (unsigned)nn;
    const bool own1 = v1 && ((unsigned)(c0 + 64 - lo) < (unsigned)nn);

    half1* const gsA = (half1*)(GSA + wid * GSS);
    half1* const gsB = (half1*)(GSB + wid * GSS);
    const int Lr = rowAct ? L : 51;
    const unsigned* const gp = (Lr & 1) ? (GSB + wid * GSS + ((Lr + 1) >> 1))
                                        : (GSA + wid * GSS + (Lr >> 1));

    float den = 0.f, ehv = 0.f;
    #pragma unroll 1
    for (int it = 0; it < NITER; ++it) {
        // ---- G sub-phase (wave-local): Ghat_c = (sum_d w*Ehat)^-tau ----
        const unsigned* ep = &Ebuf[it & 1][par][bdw];
        float a0 = 0.f, a1 = 0.f, b0 = 0.f, b1 = 0.f;
        const int eOff = cOff >> 1;              // +32 dwords for slot 1
        const int wOff = cOff * WCS ? (64 * WCS) : 0;
        #pragma unroll
        for (int t = 0; t < 24; t += 2) {
            a0 = fdot2(wc[t],     ep[t],     a0);
            a1 = fdot2(wc[t + 1], ep[t + 1], a1);
            b0 = fdot2(wc[t + (v1 ? 64 * WCS : 0)],     ep[t + eOff],     b0);
            b1 = fdot2(wc[t + 1 + (v1 ? 64 * WCS : 0)], ep[t + 1 + eOff], b1);
        }
        float l0 = __builtin_amdgcn_logf(a0 + a1);
        float l1 = __builtin_amdgcn_logf(b0 + b1);
        float g0 = __builtin_amdgcn_exp2f(-TAU * l0);
        float g1 = __builtin_amdgcn_exp2f(-TAU * l1);
        gsA[L] = (half1)g0;
        gsB[L + 1] = (half1)g0;
        if (v1) { gsA[L + 64] = (half1)g1; gsB[L + 65] = (half1)g1; }
        float yg = (own0 ? __builtin_amdgcn_exp2f(fmaf(TIR, l0, LOG_B2)) : 0.f)
                 + (own1 ? __builtin_amdgcn_exp2f(fmaf(TIR, l1, LOG_B2)) : 0.f);
        // intra-wave ordering: strip writes must land before strip reads
        asm volatile("s_waitcnt lgkmcnt(0)" ::: "memory");
        __builtin_amdgcn_sched_barrier(0);

        // ---- row sub-phase: Ehat_j = (sum_d w*Ghat)^-tau ----
        float r0 = 0.f, r1 = 0.f;
        #pragma unroll
        for (int t = 0; t < 24; t += 2) {
            r0 = fdot2(wrow[t],     gp[t],     r0);
            r1 = fdot2(wrow[t + 1], gp[t + 1], r1);
        }
        den = r0 + r1;
        float lr = __builtin_amdgcn_logf(den);
        ehv = __builtin_amdgcn_exp2f(-TAU * lr);
        if (rowAct) {
            ((half1*)Ebuf[(it + 1) & 1][0])[j + 48] = (half1)ehv;
            ((half1*)Ebuf[(it + 1) & 1][1])[j + 49] = (half1)ehv;
        }
        float yf = __builtin_amdgcn_exp2f(fmaf(TIR, lr, LOG_A2));   // 0 for idle
        float tg = dpp_sum64(yg);
        float tf = dpp_sum64(yf);
        if (L == 63) {
            s_red[(1 + 2 * it) * NWAVE + wid] = tg;
            s_red[(2 + 2 * it) * NWAVE + wid] = tf;
        }
        __syncthreads();   // the ONE barrier per iteration
    }

    // ---- uniform scalar recurrence from the 21 reduction values ----
    float fsh = -LOG_B2, gsh = 0.f;
    {
        float R[NACC];
        #pragma unroll
        for (int p = 0; p < NACC; ++p) {
            const float* rp = s_red + p * NWAVE;
            float s = ((rp[0] + rp[1]) + (rp[2] + rp[3])) + (rp[4] + rp[5]);
            R[p] = __builtin_amdgcn_logf(s);
        }
        float sminF = fsh - RHO * R[0];
        #pragma unroll
        for (int it = 0; it < NITER; ++it) {
            float Cg = TAU * (LOG_B2 - fsh) - KAPPA * sminF;
            float sg = Cg - RHO * R[1 + 2 * it];
            gsh = Cg + XI * sg;
            float sminG = (1.f + XI) * sg;
            float Cf = TAU * (LOG_A2 - gsh) - KAPPA * sminG;
            float sf = Cf - RHO * R[2 + 2 * it];
            fsh = Cf + XI * sf;
            sminF = (1.f + XI) * sf;
        }
    }

    // ---- epilogue: disparity from final wave-local G strip ----
    if (rowAct) {
        float n0 = 0.f, n1 = 0.f;
        #pragma unroll
        for (int t = 0; t < 24; ++t) {
            half2v dc; dc[0] = (half1)(float)(47 - 2 * t); dc[1] = (half1)(float)(46 - 2 * t);
            half2v wd = h2(wrow[t]) * dc;             // v_pk_mul_f16
            float& nnv = (t & 1) ? n1 : n0;
            nnv = fdot2h(wd, gp[t], nnv);
        }
        float E = __builtin_amdgcn_exp2f(fsh + gsh) * ehv;
        float mass = fmaxf(E * den, 1e-8f);
        out[(size_t)bid * WROWS + j] = (E * (n0 + n1)) / mass;
    }
}

extern "C" void kernel_launch(void* const* d_in, const int* in_sizes, int n_in,
                              void* d_out, int out_size, void* d_ws, size_t ws_size,
                              hipStream_t stream) {
    const float* scores = (const float*)d_in[0];
    float* out = (float*)d_out;
    ot_disp_kernel<<<128, NT, 0, stream>>>(scores, out);
}